// Round 4
// baseline (322.352 us; speedup 1.0000x reference)
//
#include <hip/hip_runtime.h>

// Problem constants (fixed by setup_inputs: B=64, C=16, T=32768, fp32)
#define B_BATCH 64
#define C_CH    16
#define T_LEN   32768
#define THREADS 256
#define TPT     8                        // elements per thread
#define TILE    (THREADS * TPT)          // 2048 elements per tile
#define NTILE   (T_LEN / TILE)           // 16 tiles per row
#define NROWS   (B_BATCH * C_CH)         // 1024 rows
#define NBLK    (NROWS * NTILE)          // 16384 blocks -> 64 blocks/CU of work

// ws layout: [0, 64K) float tilesum[NBLK]; [64K, 192K) double partial[NBLK].
// Every word is written before it is read (cross-dispatch ordering) -> no memset.
#define TS_OFF   0
#define PART_OFF (NBLK * 4)

// ---------------- pass 1: per-tile sum of diffs (pure streaming reduce) -------------
__global__ __launch_bounds__(THREADS, 8) void wloss_sum_kernel(
    const float* __restrict__ pred,
    const float* __restrict__ tru,
    float* __restrict__ tilesum)
{
    const int tid  = threadIdx.x;
    const int lane = tid & 63;
    const int wave = tid >> 6;
    const int row  = blockIdx.x >> 4;          // NTILE == 16
    const int g    = blockIdx.x & (NTILE - 1);

    const size_t base = (size_t)row * T_LEN + (size_t)g * TILE;
    const float4* p4 = (const float4*)(pred + base) + tid * 2;
    const float4* t4 = (const float4*)(tru  + base) + tid * 2;

    // 4 independent float4 loads issued back-to-back (max MLP, no dependencies)
    float4 a0 = p4[0], a1 = p4[1];
    float4 b0 = t4[0], b1 = t4[1];

    // per-element diffs then sum (keeps numerics in the same family as before)
    float s = (a0.x - b0.x) + (a0.y - b0.y) + (a0.z - b0.z) + (a0.w - b0.w)
            + (a1.x - b1.x) + (a1.y - b1.y) + (a1.z - b1.z) + (a1.w - b1.w);

    #pragma unroll
    for (int off = 32; off > 0; off >>= 1)
        s += __shfl_down(s, off, 64);

    __shared__ float s_w[4];
    if (lane == 0) s_w[wave] = s;
    __syncthreads();
    if (tid == 0)
        tilesum[blockIdx.x] = s_w[0] + s_w[1] + s_w[2] + s_w[3];
}

// ------------- pass 2: weighted |cumsum| per tile, carry from tile sums -------------
__global__ __launch_bounds__(THREADS, 8) void wloss_weight_kernel(
    const float* __restrict__ pred,
    const float* __restrict__ tru,
    const float* __restrict__ tilesum,
    double* __restrict__ partials)
{
    const int tid  = threadIdx.x;
    const int lane = tid & 63;
    const int wave = tid >> 6;
    const int row  = blockIdx.x >> 4;
    const int g    = blockIdx.x & (NTILE - 1);

    const size_t base = (size_t)row * T_LEN + (size_t)g * TILE;
    const float4* p4 = (const float4*)(pred + base) + tid * 2;
    const float4* t4 = (const float4*)(tru  + base) + tid * 2;

    // 4 independent float4 loads first (L3-warm from pass 1)
    float4 a0 = p4[0], a1 = p4[1];
    float4 b0 = t4[0], b1 = t4[1];

    // carry = sum of this row's earlier tile sums (uniform broadcast loads, L2-hit)
    float carry = 0.0f;
    for (int j = 0; j < g; ++j)                 // g uniform per block, <= 15
        carry += tilesum[(row << 4) + j];

    float d[TPT];
    d[0] = a0.x - b0.x; d[1] = a0.y - b0.y; d[2] = a0.z - b0.z; d[3] = a0.w - b0.w;
    d[4] = a1.x - b1.x; d[5] = a1.y - b1.y; d[6] = a1.z - b1.z; d[7] = a1.w - b1.w;
    #pragma unroll
    for (int j = 1; j < TPT; ++j) d[j] += d[j-1];   // thread-local inclusive prefix

    // wave-level scan of thread totals
    float v = d[TPT-1];
    #pragma unroll
    for (int off = 1; off < 64; off <<= 1) {
        float u = __shfl_up(v, off, 64);
        if (lane >= off) v += u;
    }
    const float texcl = v - d[TPT-1];               // in-wave exclusive prefix

    __shared__ float s_w[4];
    if (lane == 63) s_w[wave] = v;
    __syncthreads();
    float wprefix = 0.0f;
    #pragma unroll
    for (int w = 0; w < 4; ++w)
        if (w < wave) wprefix += s_w[w];

    const float excl = carry + wprefix + texcl;     // global exclusive prefix
    const int   e0   = g * TILE + tid * TPT;
    const float w0   = (float)(T_LEN - e0);
    float part = 0.0f;
    #pragma unroll
    for (int j = 0; j < TPT; ++j)
        part += fabsf(excl + d[j]) * (w0 - (float)j);

    double acc = (double)part;
    #pragma unroll
    for (int off = 32; off > 0; off >>= 1)
        acc += __shfl_down(acc, off, 64);

    __shared__ double s_d[4];
    if (lane == 0) s_d[wave] = acc;
    __syncthreads();
    if (tid == 0)
        partials[blockIdx.x] = s_d[0] + s_d[1] + s_d[2] + s_d[3];
}

// ---------------------------- pass 3: final reduction -------------------------------
__global__ __launch_bounds__(THREADS) void wloss_finalize_kernel(
    const double* __restrict__ partials, float* __restrict__ out)
{
    const int tid  = threadIdx.x;
    const int lane = tid & 63;
    const int wave = tid >> 6;

    double acc = 0.0;
    for (int i = tid; i < NBLK; i += THREADS) acc += partials[i];

    #pragma unroll
    for (int off = 32; off > 0; off >>= 1)
        acc += __shfl_down(acc, off, 64);

    __shared__ double dtot[4];
    if (lane == 0) dtot[wave] = acc;
    __syncthreads();

    if (tid == 0) {
        const double tot     = dtot[0] + dtot[1] + dtot[2] + dtot[3];
        const double tc      = (double)T_LEN * (double)C_CH;      // 524288
        const double scaling = 2.0 / (tc * (tc + 1.0));
        out[0] = (float)(tot * scaling / (double)B_BATCH);
    }
}

extern "C" void kernel_launch(void* const* d_in, const int* in_sizes, int n_in,
                              void* d_out, int out_size, void* d_ws, size_t ws_size,
                              hipStream_t stream)
{
    const float* pred = (const float*)d_in[0];
    const float* tru  = (const float*)d_in[1];
    float*  tilesum  = (float*) ((char*)d_ws + TS_OFF);
    double* partials = (double*)((char*)d_ws + PART_OFF);
    float*  out      = (float*)d_out;

    wloss_sum_kernel     <<<NBLK, THREADS, 0, stream>>>(pred, tru, tilesum);
    wloss_weight_kernel  <<<NBLK, THREADS, 0, stream>>>(pred, tru, tilesum, partials);
    wloss_finalize_kernel<<<1,    THREADS, 0, stream>>>(partials, out);
}

// Round 5
// 283.356 us; speedup vs baseline: 1.1376x; 1.1376x over previous
//
#include <hip/hip_runtime.h>

// Problem constants (fixed by setup_inputs: B=64, C=16, T=32768, fp32)
#define B_BATCH 64
#define C_CH    16
#define T_LEN   32768
#define NROWS   (B_BATCH * C_CH)   // 1024 rows -> 1024 single-wave blocks, ~4 waves/CU
#define STEP    512                // elements per step: 64 lanes x 8
#define NSTEP   (T_LEN / STEP)     // 64 steps per row

// Single pass, one row per wave. No LDS, no barriers, no inter-block traffic,
// no atomics. Memory-level parallelism comes from an explicit 8-step register
// double-buffer (16 outstanding 16B loads per wave, sustained). At 1 wave/SIMD
// the VGPR budget is ~512, so the ~190-reg payload costs no occupancy.

struct Quad { float4 p0, p1, t0, t1; };

__device__ __forceinline__ Quad ldstep(const float4* __restrict__ P,
                                       const float4* __restrict__ Tq, int s) {
    Quad q;
    q.p0 = P [s * 128];      // step stride = 512 floats = 128 float4
    q.p1 = P [s * 128 + 1];
    q.t0 = Tq[s * 128];
    q.t1 = Tq[s * 128 + 1];
    return q;
}

__global__ __launch_bounds__(64, 1) void wloss_row_kernel(
    const float* __restrict__ pred,
    const float* __restrict__ tru,
    double* __restrict__ partials)
{
    const int row  = blockIdx.x;
    const int lane = threadIdx.x;          // 0..63, one wave per block

    const float4* P  = (const float4*)(pred + (size_t)row * T_LEN) + lane * 2;
    const float4* Tq = (const float4*)(tru  + (size_t)row * T_LEN) + lane * 2;

    float  carry = 0.0f;                   // running row cumsum at step start
    double acc   = 0.0;                    // weighted-|cumsum| accumulator

    // Process one 512-elem step: diffs, thread-local prefix, wave scan, weights.
    // Scan chains of different steps are independent (ILP); only the scalar
    // 'carry += total' serializes across steps (~300cy/step, hidden by loads).
#define PROC(q, sidx)                                                        \
    {                                                                        \
        float d0 = (q).p0.x - (q).t0.x;                                      \
        float d1 = (q).p0.y - (q).t0.y;                                      \
        float d2 = (q).p0.z - (q).t0.z;                                      \
        float d3 = (q).p0.w - (q).t0.w;                                      \
        float d4 = (q).p1.x - (q).t1.x;                                      \
        float d5 = (q).p1.y - (q).t1.y;                                      \
        float d6 = (q).p1.z - (q).t1.z;                                      \
        float d7 = (q).p1.w - (q).t1.w;                                      \
        d1 += d0; d2 += d1; d3 += d2; d4 += d3; d5 += d4; d6 += d5; d7 += d6;\
        float v = d7;                                                        \
        _Pragma("unroll")                                                    \
        for (int off = 1; off < 64; off <<= 1) {                             \
            float u = __shfl_up(v, off, 64);                                 \
            if (lane >= off) v += u;                                         \
        }                                                                    \
        const float total = __shfl(v, 63, 64);                               \
        const float excl  = carry + (v - d7);                                \
        const float w0    = (float)(T_LEN - ((sidx) * STEP + lane * 8));     \
        float part = fabsf(excl + d0) *  w0                                  \
                   + fabsf(excl + d1) * (w0 - 1.0f)                          \
                   + fabsf(excl + d2) * (w0 - 2.0f)                          \
                   + fabsf(excl + d3) * (w0 - 3.0f)                          \
                   + fabsf(excl + d4) * (w0 - 4.0f)                          \
                   + fabsf(excl + d5) * (w0 - 5.0f)                          \
                   + fabsf(excl + d6) * (w0 - 6.0f)                          \
                   + fabsf(excl + d7) * (w0 - 7.0f);                         \
        acc   += (double)part;                                               \
        carry += total;                                                      \
    }

    // prologue: steps 0..3 in flight
    Quad a0 = ldstep(P, Tq, 0);
    Quad a1 = ldstep(P, Tq, 1);
    Quad a2 = ldstep(P, Tq, 2);
    Quad a3 = ldstep(P, Tq, 3);

    for (int g = 0; g < NSTEP - 8; g += 8) {      // g = 0, 8, ..., 48
        Quad b0 = ldstep(P, Tq, g + 4);           // issue next 4 steps
        Quad b1 = ldstep(P, Tq, g + 5);
        Quad b2 = ldstep(P, Tq, g + 6);
        Quad b3 = ldstep(P, Tq, g + 7);
        PROC(a0, g + 0); PROC(a1, g + 1); PROC(a2, g + 2); PROC(a3, g + 3);
        a0 = ldstep(P, Tq, g + 8);                // refill while b in flight
        a1 = ldstep(P, Tq, g + 9);
        a2 = ldstep(P, Tq, g + 10);
        a3 = ldstep(P, Tq, g + 11);
        PROC(b0, g + 4); PROC(b1, g + 5); PROC(b2, g + 6); PROC(b3, g + 7);
    }
    {   // epilogue: a holds steps 56..59; no refill past end of row
        const int g = NSTEP - 8;                  // 56
        Quad b0 = ldstep(P, Tq, g + 4);
        Quad b1 = ldstep(P, Tq, g + 5);
        Quad b2 = ldstep(P, Tq, g + 6);
        Quad b3 = ldstep(P, Tq, g + 7);
        PROC(a0, g + 0); PROC(a1, g + 1); PROC(a2, g + 2); PROC(a3, g + 3);
        PROC(b0, g + 4); PROC(b1, g + 5); PROC(b2, g + 6); PROC(b3, g + 7);
    }
#undef PROC

    // wave reduction of the double accumulator; one plain store per row
    #pragma unroll
    for (int off = 32; off > 0; off >>= 1)
        acc += __shfl_down(acc, off, 64);
    if (lane == 0) partials[row] = acc;
}

__global__ __launch_bounds__(256) void wloss_finalize_kernel(
    const double* __restrict__ partials, float* __restrict__ out)
{
    const int tid  = threadIdx.x;
    const int lane = tid & 63;
    const int wave = tid >> 6;

    double acc = 0.0;
    for (int i = tid; i < NROWS; i += 256) acc += partials[i];

    #pragma unroll
    for (int off = 32; off > 0; off >>= 1)
        acc += __shfl_down(acc, off, 64);

    __shared__ double dtot[4];
    if (lane == 0) dtot[wave] = acc;
    __syncthreads();

    if (tid == 0) {
        const double tot     = dtot[0] + dtot[1] + dtot[2] + dtot[3];
        const double tc      = (double)T_LEN * (double)C_CH;      // 524288
        const double scaling = 2.0 / (tc * (tc + 1.0));
        out[0] = (float)(tot * scaling / (double)B_BATCH);
    }
}

extern "C" void kernel_launch(void* const* d_in, const int* in_sizes, int n_in,
                              void* d_out, int out_size, void* d_ws, size_t ws_size,
                              hipStream_t stream)
{
    const float* pred = (const float*)d_in[0];
    const float* tru  = (const float*)d_in[1];
    double* partials  = (double*)d_ws;     // 1024 doubles, fully overwritten
    float*  out       = (float*)d_out;

    // No memset needed: every partial is written before finalize reads it.
    wloss_row_kernel     <<<NROWS, 64, 0, stream>>>(pred, tru, partials);
    wloss_finalize_kernel<<<1,    256, 0, stream>>>(partials, out);
}

// Round 6
// 280.343 us; speedup vs baseline: 1.1499x; 1.0107x over previous
//
#include <hip/hip_runtime.h>

// Problem constants (fixed by setup_inputs: B=64, C=16, T=32768, fp32)
#define B_BATCH 64
#define C_CH    16
#define T_LEN   32768
#define THREADS 512                  // 8 waves/block
#define NWAVE   (THREADS / 64)
#define VEC     4
#define CHUNK   (THREADS * VEC)      // 2048 elements per chunk
#define NCHUNK  (T_LEN / CHUNK)      // 16 chunks per row
#define NROWS   (B_BATCH * C_CH)     // 1024 rows -> 1024 blocks

// One row per block, 512 threads: 1024 blocks x 8 waves = 8192 waves
// = EXACTLY 32 waves/CU (100% occupancy cap), one resident generation.
// Dense float4 loads (each wave-instruction covers 1 KB contiguous, m13
// pattern) + 1-chunk register prefetch (16 VGPRs) so every wave keeps its
// next 2 KB outstanding while scanning the current chunk. launch_bounds
// (512,8) forces VGPR <= 64 so full occupancy actually materializes.
__global__ __launch_bounds__(THREADS, 8) void wloss_scan_kernel(
    const float* __restrict__ pred,
    const float* __restrict__ tru,
    double* __restrict__ partials)
{
    __shared__ float  s_wt[2][NWAVE];   // parity double-buffer: 1 barrier/chunk
    __shared__ double s_d[NWAVE];

    const int row  = blockIdx.x;
    const int tid  = threadIdx.x;
    const int lane = tid & 63;
    const int wave = tid >> 6;

    const float4* p4 = (const float4*)(pred + (size_t)row * T_LEN);
    const float4* t4 = (const float4*)(tru  + (size_t)row * T_LEN);

    float  carry = 0.0f;     // running row cumsum at chunk start (replicated)
    double acc   = 0.0;

    // prefetch chunk 0
    float4 cp = p4[tid];
    float4 ct = t4[tid];

    for (int ch = 0; ch < NCHUNK; ++ch) {
        // issue next chunk's loads FIRST (clamped on last iter: harmless re-read)
        const int nx = (ch + 1 < NCHUNK ? ch + 1 : NCHUNK - 1) * (CHUNK / VEC) + tid;
        float4 np = p4[nx];
        float4 nt = t4[nx];

        // diffs + thread-local inclusive scan of 4
        float s1 = cp.x - ct.x;
        float s2 = s1 + (cp.y - ct.y);
        float s3 = s2 + (cp.z - ct.z);
        float s4 = s3 + (cp.w - ct.w);

        // wave-level inclusive scan of thread totals
        float v = s4;
        #pragma unroll
        for (int off = 1; off < 64; off <<= 1) {
            float u = __shfl_up(v, off, 64);
            if (lane >= off) v += u;
        }

        const int par = ch & 1;
        if (lane == 63) s_wt[par][wave] = v;
        __syncthreads();

        float wpre = 0.0f, tot = 0.0f;
        #pragma unroll
        for (int w = 0; w < NWAVE; ++w) {
            float wt = s_wt[par][w];      // broadcast read, conflict-free
            if (w < wave) wpre += wt;
            tot += wt;
        }

        const float excl = carry + wpre + (v - s4);   // global exclusive prefix
        const int   e0   = ch * CHUNK + tid * VEC;
        const float w0   = (float)(T_LEN - e0);
        float part = fabsf(excl + s1) *  w0
                   + fabsf(excl + s2) * (w0 - 1.0f)
                   + fabsf(excl + s3) * (w0 - 2.0f)
                   + fabsf(excl + s4) * (w0 - 3.0f);
        acc   += (double)part;
        carry += tot;

        cp = np; ct = nt;
        // no second barrier: parity buffer + next chunk's barrier give WAR safety
    }

    // block reduction of double acc: wave shuffle-reduce, then LDS across 8 waves
    #pragma unroll
    for (int off = 32; off > 0; off >>= 1)
        acc += __shfl_down(acc, off, 64);
    if (lane == 0) s_d[wave] = acc;
    __syncthreads();

    if (tid == 0) {
        double s = 0.0;
        #pragma unroll
        for (int w = 0; w < NWAVE; ++w) s += s_d[w];
        partials[row] = s;                 // plain store, no atomics anywhere
    }
}

__global__ __launch_bounds__(256) void wloss_finalize_kernel(
    const double* __restrict__ partials, float* __restrict__ out)
{
    const int tid  = threadIdx.x;
    const int lane = tid & 63;
    const int wave = tid >> 6;

    double acc = 0.0;
    for (int i = tid; i < NROWS; i += 256) acc += partials[i];

    #pragma unroll
    for (int off = 32; off > 0; off >>= 1)
        acc += __shfl_down(acc, off, 64);

    __shared__ double dtot[4];
    if (lane == 0) dtot[wave] = acc;
    __syncthreads();

    if (tid == 0) {
        const double tot     = dtot[0] + dtot[1] + dtot[2] + dtot[3];
        const double tc      = (double)T_LEN * (double)C_CH;      // 524288
        const double scaling = 2.0 / (tc * (tc + 1.0));
        out[0] = (float)(tot * scaling / (double)B_BATCH);
    }
}

extern "C" void kernel_launch(void* const* d_in, const int* in_sizes, int n_in,
                              void* d_out, int out_size, void* d_ws, size_t ws_size,
                              hipStream_t stream)
{
    const float* pred = (const float*)d_in[0];
    const float* tru  = (const float*)d_in[1];
    double* partials  = (double*)d_ws;     // 1024 doubles, fully overwritten
    float*  out       = (float*)d_out;

    // No memset needed: every partial is written before finalize reads it.
    wloss_scan_kernel    <<<NROWS, THREADS, 0, stream>>>(pred, tru, partials);
    wloss_finalize_kernel<<<1,     256,     0, stream>>>(partials, out);
}